// Round 1
// baseline (392.276 us; speedup 1.0000x reference)
//
#include <hip/hip_runtime.h>

#define NFEAT 128

// ---------------- CSR build ----------------

__global__ __launch_bounds__(256) void k_hist(const int* __restrict__ dst,
                                              int* __restrict__ cnt, int E) {
  int i = blockIdx.x * 256 + threadIdx.x;
  if (i < E) atomicAdd(&cnt[dst[i]], 1);
}

// blocks of 1024 counts; exclusive scan within block, block total to bsum
__global__ __launch_bounds__(256) void k_scan_blocks(const int* __restrict__ cnt,
                                                     int* __restrict__ rowptr,
                                                     int* __restrict__ bsum, int n) {
  __shared__ int s[256];
  int tid = threadIdx.x;
  int idx = blockIdx.x * 1024 + tid * 4;
  int v[4];
  int sum = 0;
#pragma unroll
  for (int j = 0; j < 4; j++) {
    v[j] = (idx + j < n) ? cnt[idx + j] : 0;
    sum += v[j];
  }
  s[tid] = sum;
  __syncthreads();
  for (int off = 1; off < 256; off <<= 1) {
    int t = (tid >= off) ? s[tid - off] : 0;
    __syncthreads();
    s[tid] += t;
    __syncthreads();
  }
  if (tid == 255) bsum[blockIdx.x] = s[255];
  int run = s[tid] - sum;  // exclusive base for this thread
#pragma unroll
  for (int j = 0; j < 4; j++) {
    if (idx + j < n) rowptr[idx + j] = run;
    run += v[j];
  }
}

// single block, exclusive scan of block sums in-place (nb <= 128)
__global__ __launch_bounds__(128) void k_scan_sums(int* __restrict__ bsum, int nb) {
  __shared__ int s[128];
  int tid = threadIdx.x;
  int v = (tid < nb) ? bsum[tid] : 0;
  s[tid] = v;
  __syncthreads();
  for (int off = 1; off < 128; off <<= 1) {
    int t = (tid >= off) ? s[tid - off] : 0;
    __syncthreads();
    s[tid] += t;
    __syncthreads();
  }
  if (tid < nb) bsum[tid] = s[tid] - v;  // exclusive
}

__global__ __launch_bounds__(256) void k_scan_add(int* __restrict__ rowptr,
                                                  const int* __restrict__ bsum,
                                                  int n, int e_total) {
  int i = blockIdx.x * 256 + threadIdx.x;
  if (i < n) rowptr[i] += bsum[i >> 10];
  if (i == 0) rowptr[n] = e_total;
}

__global__ __launch_bounds__(256) void k_scatter(const int* __restrict__ src,
                                                 const int* __restrict__ dst,
                                                 const int* __restrict__ rowptr,
                                                 int* __restrict__ cursor,
                                                 int* __restrict__ csr, int E) {
  int i = blockIdx.x * 256 + threadIdx.x;
  if (i < E) {
    int d = dst[i];
    int p = atomicAdd(&cursor[d], 1);
    csr[rowptr[d] + p] = src[i];
  }
}

__global__ __launch_bounds__(256) void k_dinv(const int* __restrict__ cnt,
                                              float* __restrict__ dinv, int n) {
  int i = blockIdx.x * 256 + threadIdx.x;
  if (i < n) dinv[i] = rsqrtf((float)(cnt[i] + 1));  // +1 self loop; always > 0
}

// ---------------- fp32 GEMM: out[n,128] = A[n,128] @ W[128,128] ----------------
// block tile 64 rows x 128 cols; thread = 4 rows x 8 cols; K staged in 32-chunks.
// In-place safe: each block reads only the rows it writes, all reads before writes.

__global__ __launch_bounds__(256) void k_gemm(const float* __restrict__ A,
                                              const float* __restrict__ W,
                                              float* __restrict__ out, int n) {
  __shared__ float sW[32][128];  // 16 KB
  __shared__ float sX[64][36];   // padded: +4 breaks bank aliasing, keeps 16B align
  int tid = threadIdx.x;
  int colg = tid & 15;   // 16 col groups x 8 cols
  int rowg = tid >> 4;   // 16 row groups x 4 rows
  int c0 = colg * 8;
  int r0 = rowg * 4;
  int rowBase = blockIdx.x * 64;
  float acc[4][8] = {};

  for (int kk = 0; kk < 128; kk += 32) {
    // stage W[kk..kk+32, :]  (4096 contiguous floats)
    {
      const float4* Wv = (const float4*)(W + kk * 128);
      float4* sWv = (float4*)(&sW[0][0]);
#pragma unroll
      for (int j = 0; j < 4; j++) sWv[tid + j * 256] = Wv[tid + j * 256];
    }
    // stage X[rowBase..+64, kk..kk+32]: 4 threads/row, 8 floats each
    {
      int row = tid >> 2;
      int tr = tid & 3;
      int gr = rowBase + row;
      float4 a0 = {0, 0, 0, 0}, a1 = {0, 0, 0, 0};
      if (gr < n) {
        const float* Ap = A + (size_t)gr * NFEAT + kk + tr * 8;
        a0 = *(const float4*)Ap;
        a1 = *(const float4*)(Ap + 4);
      }
      *(float4*)(&sX[row][tr * 8]) = a0;
      *(float4*)(&sX[row][tr * 8 + 4]) = a1;
    }
    __syncthreads();
#pragma unroll
    for (int k = 0; k < 32; k++) {
      float a[4];
#pragma unroll
      for (int r = 0; r < 4; r++) a[r] = sX[r0 + r][k];
      float4 w0 = *(const float4*)(&sW[k][c0]);
      float4 w1 = *(const float4*)(&sW[k][c0 + 4]);
      float w[8] = {w0.x, w0.y, w0.z, w0.w, w1.x, w1.y, w1.z, w1.w};
#pragma unroll
      for (int r = 0; r < 4; r++)
#pragma unroll
        for (int c = 0; c < 8; c++) acc[r][c] = fmaf(a[r], w[c], acc[r][c]);
    }
    __syncthreads();
  }

#pragma unroll
  for (int r = 0; r < 4; r++) {
    int gr = rowBase + r0 + r;
    if (gr < n) {
      float4 o0 = {acc[r][0], acc[r][1], acc[r][2], acc[r][3]};
      float4 o1 = {acc[r][4], acc[r][5], acc[r][6], acc[r][7]};
      *(float4*)(out + (size_t)gr * NFEAT + c0) = o0;
      *(float4*)(out + (size_t)gr * NFEAT + c0 + 4) = o1;
    }
  }
}

// ---------------- aggregation: one wave per node ----------------
// out[d] = dinv[d] * ( sum_{s in CSR[d]} dinv[s]*h[s] + dinv[d]*h[d] ) + b  [, relu]

__global__ __launch_bounds__(256) void k_agg(const float* __restrict__ h,
                                             const float* __restrict__ dinv,
                                             const int* __restrict__ rowptr,
                                             const int* __restrict__ csr,
                                             const float* __restrict__ bias,
                                             float* __restrict__ out, int n, int relu) {
  int node = blockIdx.x * 4 + (threadIdx.x >> 6);
  if (node >= n) return;
  int lane = threadIdx.x & 63;
  int c = lane * 2;
  float di = dinv[node];
  const float2 hs = *(const float2*)(h + (size_t)node * NFEAT + c);
  float ax = di * hs.x, ay = di * hs.y;  // self-loop term (x dinv[d] again at end)
  int e = rowptr[node], end = rowptr[node + 1];
  for (; e + 1 < end; e += 2) {
    int s0 = csr[e], s1 = csr[e + 1];
    float w0 = dinv[s0], w1 = dinv[s1];
    float2 h0 = *(const float2*)(h + (size_t)s0 * NFEAT + c);
    float2 h1 = *(const float2*)(h + (size_t)s1 * NFEAT + c);
    ax += w0 * h0.x + w1 * h1.x;
    ay += w0 * h0.y + w1 * h1.y;
  }
  if (e < end) {
    int s0 = csr[e];
    float w0 = dinv[s0];
    float2 h0 = *(const float2*)(h + (size_t)s0 * NFEAT + c);
    ax += w0 * h0.x;
    ay += w0 * h0.y;
  }
  float ox = di * ax + bias[c];
  float oy = di * ay + bias[c + 1];
  if (relu) {
    ox = fmaxf(ox, 0.f);
    oy = fmaxf(oy, 0.f);
  }
  float2 o = {ox, oy};
  *(float2*)(out + (size_t)node * NFEAT + c) = o;
}

// ---------------- launch ----------------

extern "C" void kernel_launch(void* const* d_in, const int* in_sizes, int n_in,
                              void* d_out, int out_size, void* d_ws, size_t ws_size,
                              hipStream_t stream) {
  const float* x = (const float*)d_in[0];
  const float* W1 = (const float*)d_in[1];
  const float* b1 = (const float*)d_in[2];
  const float* W2 = (const float*)d_in[3];
  const float* b2 = (const float*)d_in[4];
  const int* ei = (const int*)d_in[5];

  const int N = in_sizes[0] / NFEAT;
  const int E = in_sizes[5] / 2;
  const int* srcIdx = ei;
  const int* dstIdx = ei + E;

  char* p = (char*)d_ws;
  auto alloc = [&](size_t bytes) {
    char* r = p;
    p += (bytes + 255) & ~(size_t)255;
    return r;
  };
  int* cnt = (int*)alloc((size_t)N * 4);
  int* cursor = (int*)alloc((size_t)N * 4);
  float* dinv = (float*)alloc((size_t)N * 4);
  int* rowptr = (int*)alloc((size_t)(N + 1) * 4);
  int* bsum = (int*)alloc(512);
  int* csr = (int*)alloc((size_t)E * 4);
  float* tmp1 = (float*)alloc((size_t)N * NFEAT * 4);
  float* out = (float*)d_out;

  // zero cnt + cursor (contiguous regions)
  hipMemsetAsync(cnt, 0, (size_t)((char*)dinv - (char*)cnt), stream);

  int gE = (E + 255) / 256;
  int gN = (N + 255) / 256;
  int nb = (N + 1023) / 1024;

  k_hist<<<gE, 256, 0, stream>>>(dstIdx, cnt, E);
  k_scan_blocks<<<nb, 256, 0, stream>>>(cnt, rowptr, bsum, N);
  k_scan_sums<<<1, 128, 0, stream>>>(bsum, nb);
  k_scan_add<<<gN, 256, 0, stream>>>(rowptr, bsum, N, E);
  k_scatter<<<gE, 256, 0, stream>>>(srcIdx, dstIdx, rowptr, cursor, csr, E);
  k_dinv<<<gN, 256, 0, stream>>>(cnt, dinv, N);

  int gG = (N + 63) / 64;
  int gA = (N + 3) / 4;

  // layer 1: g1: x -> d_out ; a1: d_out -> tmp1 (+b1, relu)
  k_gemm<<<gG, 256, 0, stream>>>(x, W1, out, N);
  k_agg<<<gA, 256, 0, stream>>>(out, dinv, rowptr, csr, b1, tmp1, N, 1);
  // layer 2: g2: tmp1 -> tmp1 (in-place safe) ; a2: tmp1 -> d_out (+b2)
  k_gemm<<<gG, 256, 0, stream>>>(tmp1, W2, tmp1, N);
  k_agg<<<gA, 256, 0, stream>>>(tmp1, dinv, rowptr, csr, b2, out, N, 0);
}

// Round 2
// 364.316 us; speedup vs baseline: 1.0767x; 1.0767x over previous
//
#include <hip/hip_runtime.h>

#define NFEAT 128

// ---------------- CSR build ----------------

__global__ __launch_bounds__(256) void k_hist(const int* __restrict__ dst,
                                              int* __restrict__ cnt, int E) {
  int i = blockIdx.x * 256 + threadIdx.x;
  if (i < E) atomicAdd(&cnt[dst[i]], 1);
}

__global__ __launch_bounds__(256) void k_dinv(const int* __restrict__ cnt,
                                              float* __restrict__ dinv, int n) {
  int i = blockIdx.x * 256 + threadIdx.x;
  if (i < n) dinv[i] = rsqrtf((float)(cnt[i] + 1));  // +1 self loop; always > 0
}

// blocks of 1024 counts; exclusive scan within block, block total to bsum
__global__ __launch_bounds__(256) void k_scan_blocks(const int* __restrict__ cnt,
                                                     int* __restrict__ rowptr,
                                                     int* __restrict__ bsum, int n) {
  __shared__ int s[256];
  int tid = threadIdx.x;
  int idx = blockIdx.x * 1024 + tid * 4;
  int v[4];
  int sum = 0;
#pragma unroll
  for (int j = 0; j < 4; j++) {
    v[j] = (idx + j < n) ? cnt[idx + j] : 0;
    sum += v[j];
  }
  s[tid] = sum;
  __syncthreads();
  for (int off = 1; off < 256; off <<= 1) {
    int t = (tid >= off) ? s[tid - off] : 0;
    __syncthreads();
    s[tid] += t;
    __syncthreads();
  }
  if (tid == 255) bsum[blockIdx.x] = s[255];
  int run = s[tid] - sum;  // exclusive base for this thread
#pragma unroll
  for (int j = 0; j < 4; j++) {
    if (idx + j < n) rowptr[idx + j] = run;
    run += v[j];
  }
}

// single block, exclusive scan of block sums in-place (nb <= 128)
__global__ __launch_bounds__(128) void k_scan_sums(int* __restrict__ bsum, int nb) {
  __shared__ int s[128];
  int tid = threadIdx.x;
  int v = (tid < nb) ? bsum[tid] : 0;
  s[tid] = v;
  __syncthreads();
  for (int off = 1; off < 128; off <<= 1) {
    int t = (tid >= off) ? s[tid - off] : 0;
    __syncthreads();
    s[tid] += t;
    __syncthreads();
  }
  if (tid < nb) bsum[tid] = s[tid] - v;  // exclusive
}

__global__ __launch_bounds__(256) void k_scan_add(int* __restrict__ rowptr,
                                                  const int* __restrict__ bsum,
                                                  int n, int e_total) {
  int i = blockIdx.x * 256 + threadIdx.x;
  if (i < n) rowptr[i] += bsum[i >> 10];
  if (i == 0) rowptr[n] = e_total;
}

// scatter edge -> CSR slot, packing (src, dinv[src]) so agg never gathers dinv
__global__ __launch_bounds__(256) void k_scatter(const int* __restrict__ src,
                                                 const int* __restrict__ dst,
                                                 const int* __restrict__ rowptr,
                                                 const float* __restrict__ dinv,
                                                 int* __restrict__ cursor,
                                                 int2* __restrict__ csr2, int E) {
  int i = blockIdx.x * 256 + threadIdx.x;
  if (i < E) {
    int d = dst[i];
    int s = src[i];
    int p = atomicAdd(&cursor[d], 1);
    int2 v;
    v.x = s;
    v.y = __float_as_int(dinv[s]);
    csr2[rowptr[d] + p] = v;
  }
}

// ---------------- fp32 GEMM: out[n,128] = A[n,128] @ W[128,128] ----------------
// block tile 64 rows x 128 cols; thread = 4 rows x 8 cols; K staged in 32-chunks.
// In-place safe: each block reads only the rows it writes, all reads before writes.

__global__ __launch_bounds__(256) void k_gemm(const float* __restrict__ A,
                                              const float* __restrict__ W,
                                              float* __restrict__ out, int n) {
  __shared__ float sW[32][128];  // 16 KB
  __shared__ float sX[64][36];   // padded: +4 breaks bank aliasing, keeps 16B align
  int tid = threadIdx.x;
  int colg = tid & 15;   // 16 col groups x 8 cols
  int rowg = tid >> 4;   // 16 row groups x 4 rows
  int c0 = colg * 8;
  int r0 = rowg * 4;
  int rowBase = blockIdx.x * 64;
  float acc[4][8] = {};

  for (int kk = 0; kk < 128; kk += 32) {
    // stage W[kk..kk+32, :]  (4096 contiguous floats)
    {
      const float4* Wv = (const float4*)(W + kk * 128);
      float4* sWv = (float4*)(&sW[0][0]);
#pragma unroll
      for (int j = 0; j < 4; j++) sWv[tid + j * 256] = Wv[tid + j * 256];
    }
    // stage X[rowBase..+64, kk..kk+32]: 4 threads/row, 8 floats each
    {
      int row = tid >> 2;
      int tr = tid & 3;
      int gr = rowBase + row;
      float4 a0 = {0, 0, 0, 0}, a1 = {0, 0, 0, 0};
      if (gr < n) {
        const float* Ap = A + (size_t)gr * NFEAT + kk + tr * 8;
        a0 = *(const float4*)Ap;
        a1 = *(const float4*)(Ap + 4);
      }
      *(float4*)(&sX[row][tr * 8]) = a0;
      *(float4*)(&sX[row][tr * 8 + 4]) = a1;
    }
    __syncthreads();
#pragma unroll
    for (int k = 0; k < 32; k++) {
      float a[4];
#pragma unroll
      for (int r = 0; r < 4; r++) a[r] = sX[r0 + r][k];
      float4 w0 = *(const float4*)(&sW[k][c0]);
      float4 w1 = *(const float4*)(&sW[k][c0 + 4]);
      float w[8] = {w0.x, w0.y, w0.z, w0.w, w1.x, w1.y, w1.z, w1.w};
#pragma unroll
      for (int r = 0; r < 4; r++)
#pragma unroll
        for (int c = 0; c < 8; c++) acc[r][c] = fmaf(a[r], w[c], acc[r][c]);
    }
    __syncthreads();
  }

#pragma unroll
  for (int r = 0; r < 4; r++) {
    int gr = rowBase + r0 + r;
    if (gr < n) {
      float4 o0 = {acc[r][0], acc[r][1], acc[r][2], acc[r][3]};
      float4 o1 = {acc[r][4], acc[r][5], acc[r][6], acc[r][7]};
      *(float4*)(out + (size_t)gr * NFEAT + c0) = o0;
      *(float4*)(out + (size_t)gr * NFEAT + c0 + 4) = o1;
    }
  }
}

// ---------------- aggregation: 32 lanes per node, 2 nodes per wave ----------------
// out[d] = dinv[d] * ( sum_{(s,w) in CSR2[d]} w*h[s] + dinv[d]*h[d] ) + b  [, relu]
// float4 per lane covers all 128 cols with 32 lanes. Unroll-4 edge loop: with 2
// nodes/wave that's up to 8 independent h-row gathers in flight per wave.

__global__ __launch_bounds__(256) void k_agg(const float* __restrict__ h,
                                             const float* __restrict__ dinv,
                                             const int* __restrict__ rowptr,
                                             const int2* __restrict__ csr2,
                                             const float* __restrict__ bias,
                                             float* __restrict__ out, int n, int relu) {
  int node = blockIdx.x * 8 + (threadIdx.x >> 5);
  if (node >= n) return;
  int lane = threadIdx.x & 31;
  int c = lane * 4;
  float di = dinv[node];
  float4 hs = *(const float4*)(h + (size_t)node * NFEAT + c);
  float ax = di * hs.x, ay = di * hs.y, az = di * hs.z, aw = di * hs.w;

  int e = rowptr[node], end = rowptr[node + 1];
  for (; e + 3 < end; e += 4) {
    int2 p0 = csr2[e], p1 = csr2[e + 1], p2 = csr2[e + 2], p3 = csr2[e + 3];
    float w0 = __int_as_float(p0.y), w1 = __int_as_float(p1.y);
    float w2 = __int_as_float(p2.y), w3 = __int_as_float(p3.y);
    float4 h0 = *(const float4*)(h + (size_t)p0.x * NFEAT + c);
    float4 h1 = *(const float4*)(h + (size_t)p1.x * NFEAT + c);
    float4 h2 = *(const float4*)(h + (size_t)p2.x * NFEAT + c);
    float4 h3 = *(const float4*)(h + (size_t)p3.x * NFEAT + c);
    ax = fmaf(w0, h0.x, ax); ay = fmaf(w0, h0.y, ay); az = fmaf(w0, h0.z, az); aw = fmaf(w0, h0.w, aw);
    ax = fmaf(w1, h1.x, ax); ay = fmaf(w1, h1.y, ay); az = fmaf(w1, h1.z, az); aw = fmaf(w1, h1.w, aw);
    ax = fmaf(w2, h2.x, ax); ay = fmaf(w2, h2.y, ay); az = fmaf(w2, h2.z, az); aw = fmaf(w2, h2.w, aw);
    ax = fmaf(w3, h3.x, ax); ay = fmaf(w3, h3.y, ay); az = fmaf(w3, h3.z, az); aw = fmaf(w3, h3.w, aw);
  }
  for (; e < end; ++e) {
    int2 p0 = csr2[e];
    float w0 = __int_as_float(p0.y);
    float4 h0 = *(const float4*)(h + (size_t)p0.x * NFEAT + c);
    ax = fmaf(w0, h0.x, ax); ay = fmaf(w0, h0.y, ay); az = fmaf(w0, h0.z, az); aw = fmaf(w0, h0.w, aw);
  }

  float4 b = *(const float4*)(bias + c);
  float4 o;
  o.x = fmaf(di, ax, b.x);
  o.y = fmaf(di, ay, b.y);
  o.z = fmaf(di, az, b.z);
  o.w = fmaf(di, aw, b.w);
  if (relu) {
    o.x = fmaxf(o.x, 0.f);
    o.y = fmaxf(o.y, 0.f);
    o.z = fmaxf(o.z, 0.f);
    o.w = fmaxf(o.w, 0.f);
  }
  *(float4*)(out + (size_t)node * NFEAT + c) = o;
}

// ---------------- launch ----------------

extern "C" void kernel_launch(void* const* d_in, const int* in_sizes, int n_in,
                              void* d_out, int out_size, void* d_ws, size_t ws_size,
                              hipStream_t stream) {
  const float* x = (const float*)d_in[0];
  const float* W1 = (const float*)d_in[1];
  const float* b1 = (const float*)d_in[2];
  const float* W2 = (const float*)d_in[3];
  const float* b2 = (const float*)d_in[4];
  const int* ei = (const int*)d_in[5];

  const int N = in_sizes[0] / NFEAT;
  const int E = in_sizes[5] / 2;
  const int* srcIdx = ei;
  const int* dstIdx = ei + E;

  char* p = (char*)d_ws;
  auto alloc = [&](size_t bytes) {
    char* r = p;
    p += (bytes + 255) & ~(size_t)255;
    return r;
  };
  int* cnt = (int*)alloc((size_t)N * 4);
  int* cursor = (int*)alloc((size_t)N * 4);
  float* dinv = (float*)alloc((size_t)N * 4);
  int* rowptr = (int*)alloc((size_t)(N + 1) * 4);
  int* bsum = (int*)alloc(512);
  int2* csr2 = (int2*)alloc((size_t)E * 8);
  float* tmp1 = (float*)alloc((size_t)N * NFEAT * 4);
  float* out = (float*)d_out;

  // zero cnt + cursor (contiguous regions)
  hipMemsetAsync(cnt, 0, (size_t)((char*)dinv - (char*)cnt), stream);

  int gE = (E + 255) / 256;
  int gN = (N + 255) / 256;
  int nb = (N + 1023) / 1024;

  k_hist<<<gE, 256, 0, stream>>>(dstIdx, cnt, E);
  k_dinv<<<gN, 256, 0, stream>>>(cnt, dinv, N);  // cnt final after hist
  k_scan_blocks<<<nb, 256, 0, stream>>>(cnt, rowptr, bsum, N);
  k_scan_sums<<<1, 128, 0, stream>>>(bsum, nb);
  k_scan_add<<<gN, 256, 0, stream>>>(rowptr, bsum, N, E);
  k_scatter<<<gE, 256, 0, stream>>>(srcIdx, dstIdx, rowptr, dinv, cursor, csr2, E);

  int gG = (N + 63) / 64;
  int gA = (N + 7) / 8;

  // layer 1: g1: x -> d_out ; a1: d_out -> tmp1 (+b1, relu)
  k_gemm<<<gG, 256, 0, stream>>>(x, W1, out, N);
  k_agg<<<gA, 256, 0, stream>>>(out, dinv, rowptr, csr2, b1, tmp1, N, 1);
  // layer 2: g2: tmp1 -> tmp1 (in-place safe) ; a2: tmp1 -> d_out (+b2)
  k_gemm<<<gG, 256, 0, stream>>>(tmp1, W2, tmp1, N);
  k_agg<<<gA, 256, 0, stream>>>(tmp1, dinv, rowptr, csr2, b2, out, N, 0);
}

// Round 3
// 279.555 us; speedup vs baseline: 1.4032x; 1.3032x over previous
//
#include <hip/hip_runtime.h>

#define NFEAT 128

typedef __attribute__((ext_vector_type(8))) short bf16x8;
typedef __attribute__((ext_vector_type(4))) float f32x4;

__device__ inline ushort f2b(float v) {  // fp32 -> bf16 RNE
  unsigned u = __builtin_bit_cast(unsigned, v);
  unsigned r = (u + 0x7FFFu + ((u >> 16) & 1u)) >> 16;
  return (ushort)r;
}

// ---------------- CSR build ----------------

__global__ __launch_bounds__(256) void k_hist(const int* __restrict__ dst,
                                              int* __restrict__ cnt, int E) {
  int i = blockIdx.x * 256 + threadIdx.x;
  if (i < E) atomicAdd(&cnt[dst[i]], 1);
}

__global__ __launch_bounds__(256) void k_dinv(const int* __restrict__ cnt,
                                              float* __restrict__ dinv, int n) {
  int i = blockIdx.x * 256 + threadIdx.x;
  if (i < n) dinv[i] = rsqrtf((float)(cnt[i] + 1));  // +1 self loop; always > 0
}

__global__ __launch_bounds__(256) void k_scan_blocks(const int* __restrict__ cnt,
                                                     int* __restrict__ rowptr,
                                                     int* __restrict__ bsum, int n) {
  __shared__ int s[256];
  int tid = threadIdx.x;
  int idx = blockIdx.x * 1024 + tid * 4;
  int v[4];
  int sum = 0;
#pragma unroll
  for (int j = 0; j < 4; j++) {
    v[j] = (idx + j < n) ? cnt[idx + j] : 0;
    sum += v[j];
  }
  s[tid] = sum;
  __syncthreads();
  for (int off = 1; off < 256; off <<= 1) {
    int t = (tid >= off) ? s[tid - off] : 0;
    __syncthreads();
    s[tid] += t;
    __syncthreads();
  }
  if (tid == 255) bsum[blockIdx.x] = s[255];
  int run = s[tid] - sum;
#pragma unroll
  for (int j = 0; j < 4; j++) {
    if (idx + j < n) rowptr[idx + j] = run;
    run += v[j];
  }
}

__global__ __launch_bounds__(128) void k_scan_sums(int* __restrict__ bsum, int nb) {
  __shared__ int s[128];
  int tid = threadIdx.x;
  int v = (tid < nb) ? bsum[tid] : 0;
  s[tid] = v;
  __syncthreads();
  for (int off = 1; off < 128; off <<= 1) {
    int t = (tid >= off) ? s[tid - off] : 0;
    __syncthreads();
    s[tid] += t;
    __syncthreads();
  }
  if (tid < nb) bsum[tid] = s[tid] - v;
}

__global__ __launch_bounds__(256) void k_scan_add(int* __restrict__ rowptr,
                                                  const int* __restrict__ bsum,
                                                  int n, int e_total) {
  int i = blockIdx.x * 256 + threadIdx.x;
  if (i < n) rowptr[i] += bsum[i >> 10];
  if (i == 0) rowptr[n] = e_total;
}

__global__ __launch_bounds__(256) void k_scatter(const int* __restrict__ src,
                                                 const int* __restrict__ dst,
                                                 const int* __restrict__ rowptr,
                                                 const float* __restrict__ dinv,
                                                 int* __restrict__ cursor,
                                                 int2* __restrict__ csr2, int E) {
  int i = blockIdx.x * 256 + threadIdx.x;
  if (i < E) {
    int d = dst[i];
    int s = src[i];
    int p = atomicAdd(&cursor[d], 1);
    int2 v;
    v.x = s;
    v.y = __float_as_int(dinv[s]);
    csr2[rowptr[d] + p] = v;
  }
}

// ---------------- casts ----------------

// x fp32 -> bf16, 8 elems/thread
__global__ __launch_bounds__(256) void k_cast_x(const float* __restrict__ x,
                                                ushort* __restrict__ xb, int total8) {
  int i = blockIdx.x * 256 + threadIdx.x;
  if (i >= total8) return;
  const float4* p = (const float4*)(x + (size_t)i * 8);
  float4 a = p[0], b = p[1];
  uint4 o;
  o.x = f2b(a.x) | ((unsigned)f2b(a.y) << 16);
  o.y = f2b(a.z) | ((unsigned)f2b(a.w) << 16);
  o.z = f2b(b.x) | ((unsigned)f2b(b.y) << 16);
  o.w = f2b(b.z) | ((unsigned)f2b(b.w) << 16);
  *(uint4*)(xb + (size_t)i * 8) = o;
}

// W[128][128] fp32 -> WT[n][k] bf16 (transpose + cast); grid 64 x 256
__global__ __launch_bounds__(256) void k_cast_wt(const float* __restrict__ W,
                                                 ushort* __restrict__ WT) {
  int idx = blockIdx.x * 256 + threadIdx.x;  // 0..16383
  int k = idx >> 7, nn = idx & 127;
  WT[nn * 128 + k] = f2b(W[idx]);
}

// ---------------- bf16 MFMA GEMM: out[n,128] = A[n,128] @ W[128,128] ----------------
// Block = 128 rows, 4 waves x 32 rows, all 128 cols. W^T staged once in LDS
// (pad 136: ds_read_b128 lands 2-way on banks = free). A-frags straight from
// global to registers (reused across 8 col-tiles). fp32 accum, bf16 out.

__global__ __launch_bounds__(256) void k_gemm_bf16(const ushort* __restrict__ A,
                                                   const ushort* __restrict__ WT,
                                                   ushort* __restrict__ out, int n) {
  __shared__ ushort sW[128][136];  // 34816 B -> 4 blocks/CU
  int tid = threadIdx.x;
  {
    int r = tid >> 1, hh = tid & 1;
    const uint4* srcp = (const uint4*)(WT + r * 128 + hh * 64);
    uint4* dstp = (uint4*)(&sW[r][hh * 64]);
#pragma unroll
    for (int j = 0; j < 8; j++) dstp[j] = srcp[j];
  }
  __syncthreads();

  int wave = tid >> 6;
  int lane = tid & 63;
  int l16 = lane & 15;
  int quad = lane >> 4;
  int rowBase = blockIdx.x * 128 + wave * 32;

  // A-frags: A[m = l16][k = quad*8 + j], 2 row-tiles x 4 k-steps
  bf16x8 afrag[2][4];
#pragma unroll
  for (int rt = 0; rt < 2; rt++) {
    int row = rowBase + rt * 16 + l16;
    row = min(row, n - 1);  // clamp: OOB rows compute garbage, never stored
    const ushort* Ap = A + (size_t)row * NFEAT + quad * 8;
#pragma unroll
    for (int ks = 0; ks < 4; ks++) afrag[rt][ks] = *(const bf16x8*)(Ap + ks * 32);
  }

#pragma unroll
  for (int ct = 0; ct < 8; ct++) {
    // B-frags: B[k = quad*8+j][nn = l16] == sW[ct*16+l16][k]
    bf16x8 bfrag[4];
#pragma unroll
    for (int ks = 0; ks < 4; ks++)
      bfrag[ks] = *(const bf16x8*)(&sW[ct * 16 + l16][ks * 32 + quad * 8]);
    f32x4 acc[2] = {{0.f, 0.f, 0.f, 0.f}, {0.f, 0.f, 0.f, 0.f}};
#pragma unroll
    for (int rt = 0; rt < 2; rt++)
#pragma unroll
      for (int ks = 0; ks < 4; ks++)
        acc[rt] = __builtin_amdgcn_mfma_f32_16x16x32_bf16(afrag[rt][ks], bfrag[ks],
                                                          acc[rt], 0, 0, 0);
    // C/D: col = l16, row = quad*4 + r
#pragma unroll
    for (int rt = 0; rt < 2; rt++)
#pragma unroll
      for (int r = 0; r < 4; r++) {
        int row = rowBase + rt * 16 + quad * 4 + r;
        if (row < n) out[(size_t)row * NFEAT + ct * 16 + l16] = f2b(acc[rt][r]);
      }
  }
}

// ---------------- aggregation: 32 lanes/node, 2 nodes/wave, bf16 h ----------------
// out[d] = dinv[d]*( sum w*h[s] + dinv[d]*h[d] ) + b ; relu+bf16 out or fp32 out

__global__ __launch_bounds__(256) void k_agg_bf16(const ushort* __restrict__ h,
                                                  const float* __restrict__ dinv,
                                                  const int* __restrict__ rowptr,
                                                  const int2* __restrict__ csr2,
                                                  const float* __restrict__ bias,
                                                  ushort* __restrict__ out_bf,
                                                  float* __restrict__ out_f32,
                                                  int n, int relu_bf) {
  int node = blockIdx.x * 8 + (threadIdx.x >> 5);
  if (node >= n) return;
  int lane = threadIdx.x & 31;
  int c = lane * 4;
  float di = dinv[node];

  uint2 hv = *(const uint2*)(h + (size_t)node * NFEAT + c);
  float a0 = di * __uint_as_float(hv.x << 16);
  float a1 = di * __uint_as_float(hv.x & 0xffff0000u);
  float a2 = di * __uint_as_float(hv.y << 16);
  float a3 = di * __uint_as_float(hv.y & 0xffff0000u);

  int e = rowptr[node], end = rowptr[node + 1];
  for (; e + 3 < end; e += 4) {
    int2 p0 = csr2[e], p1 = csr2[e + 1], p2 = csr2[e + 2], p3 = csr2[e + 3];
    uint2 h0 = *(const uint2*)(h + (size_t)p0.x * NFEAT + c);
    uint2 h1 = *(const uint2*)(h + (size_t)p1.x * NFEAT + c);
    uint2 h2 = *(const uint2*)(h + (size_t)p2.x * NFEAT + c);
    uint2 h3 = *(const uint2*)(h + (size_t)p3.x * NFEAT + c);
    float w0 = __int_as_float(p0.y), w1 = __int_as_float(p1.y);
    float w2 = __int_as_float(p2.y), w3 = __int_as_float(p3.y);
    a0 = fmaf(w0, __uint_as_float(h0.x << 16), a0);
    a1 = fmaf(w0, __uint_as_float(h0.x & 0xffff0000u), a1);
    a2 = fmaf(w0, __uint_as_float(h0.y << 16), a2);
    a3 = fmaf(w0, __uint_as_float(h0.y & 0xffff0000u), a3);
    a0 = fmaf(w1, __uint_as_float(h1.x << 16), a0);
    a1 = fmaf(w1, __uint_as_float(h1.x & 0xffff0000u), a1);
    a2 = fmaf(w1, __uint_as_float(h1.y << 16), a2);
    a3 = fmaf(w1, __uint_as_float(h1.y & 0xffff0000u), a3);
    a0 = fmaf(w2, __uint_as_float(h2.x << 16), a0);
    a1 = fmaf(w2, __uint_as_float(h2.x & 0xffff0000u), a1);
    a2 = fmaf(w2, __uint_as_float(h2.y << 16), a2);
    a3 = fmaf(w2, __uint_as_float(h2.y & 0xffff0000u), a3);
    a0 = fmaf(w3, __uint_as_float(h3.x << 16), a0);
    a1 = fmaf(w3, __uint_as_float(h3.x & 0xffff0000u), a1);
    a2 = fmaf(w3, __uint_as_float(h3.y << 16), a2);
    a3 = fmaf(w3, __uint_as_float(h3.y & 0xffff0000u), a3);
  }
  for (; e < end; ++e) {
    int2 p0 = csr2[e];
    uint2 h0 = *(const uint2*)(h + (size_t)p0.x * NFEAT + c);
    float w0 = __int_as_float(p0.y);
    a0 = fmaf(w0, __uint_as_float(h0.x << 16), a0);
    a1 = fmaf(w0, __uint_as_float(h0.x & 0xffff0000u), a1);
    a2 = fmaf(w0, __uint_as_float(h0.y << 16), a2);
    a3 = fmaf(w0, __uint_as_float(h0.y & 0xffff0000u), a3);
  }

  float4 b = *(const float4*)(bias + c);
  float o0 = fmaf(di, a0, b.x);
  float o1 = fmaf(di, a1, b.y);
  float o2 = fmaf(di, a2, b.z);
  float o3 = fmaf(di, a3, b.w);
  if (relu_bf) {
    o0 = fmaxf(o0, 0.f); o1 = fmaxf(o1, 0.f);
    o2 = fmaxf(o2, 0.f); o3 = fmaxf(o3, 0.f);
    uint2 pk;
    pk.x = f2b(o0) | ((unsigned)f2b(o1) << 16);
    pk.y = f2b(o2) | ((unsigned)f2b(o3) << 16);
    *(uint2*)(out_bf + (size_t)node * NFEAT + c) = pk;
  } else {
    float4 o = {o0, o1, o2, o3};
    *(float4*)(out_f32 + (size_t)node * NFEAT + c) = o;
  }
}

// ---------------- launch ----------------

extern "C" void kernel_launch(void* const* d_in, const int* in_sizes, int n_in,
                              void* d_out, int out_size, void* d_ws, size_t ws_size,
                              hipStream_t stream) {
  const float* x = (const float*)d_in[0];
  const float* W1 = (const float*)d_in[1];
  const float* b1 = (const float*)d_in[2];
  const float* W2 = (const float*)d_in[3];
  const float* b2 = (const float*)d_in[4];
  const int* ei = (const int*)d_in[5];

  const int N = in_sizes[0] / NFEAT;
  const int E = in_sizes[5] / 2;
  const int* srcIdx = ei;
  const int* dstIdx = ei + E;

  char* p = (char*)d_ws;
  auto alloc = [&](size_t bytes) {
    char* r = p;
    p += (bytes + 255) & ~(size_t)255;
    return r;
  };
  int* cnt = (int*)alloc((size_t)N * 4);
  int* cursor = (int*)alloc((size_t)N * 4);
  float* dinv = (float*)alloc((size_t)N * 4);
  int* rowptr = (int*)alloc((size_t)(N + 1) * 4);
  int* bsum = (int*)alloc(512);
  int2* csr2 = (int2*)alloc((size_t)E * 8);
  ushort* WT1 = (ushort*)alloc(NFEAT * NFEAT * 2);
  ushort* WT2 = (ushort*)alloc(NFEAT * NFEAT * 2);
  ushort* t1 = (ushort*)alloc((size_t)N * NFEAT * 2);   // agg1 out (bf16)
  ushort* h2 = (ushort*)alloc((size_t)N * NFEAT * 2);   // gemm2 out (bf16)
  // xb and h1 live inside d_out (both dead before agg2 overwrites d_out)
  ushort* xb = (ushort*)d_out;
  ushort* h1 = xb + (size_t)N * NFEAT;
  float* out = (float*)d_out;

  hipMemsetAsync(cnt, 0, (size_t)((char*)dinv - (char*)cnt), stream);

  int gE = (E + 255) / 256;
  int gN = (N + 255) / 256;
  int nb = (N + 1023) / 1024;

  k_hist<<<gE, 256, 0, stream>>>(dstIdx, cnt, E);
  k_dinv<<<gN, 256, 0, stream>>>(cnt, dinv, N);
  k_scan_blocks<<<nb, 256, 0, stream>>>(cnt, rowptr, bsum, N);
  k_scan_sums<<<1, 128, 0, stream>>>(bsum, nb);
  k_scan_add<<<gN, 256, 0, stream>>>(rowptr, bsum, N, E);
  k_scatter<<<gE, 256, 0, stream>>>(srcIdx, dstIdx, rowptr, dinv, cursor, csr2, E);

  k_cast_wt<<<64, 256, 0, stream>>>(W1, WT1);
  k_cast_wt<<<64, 256, 0, stream>>>(W2, WT2);
  int t8 = N * NFEAT / 8;
  k_cast_x<<<(t8 + 255) / 256, 256, 0, stream>>>(x, xb, t8);

  int gG = (N + 127) / 128;
  int gA = (N + 7) / 8;

  k_gemm_bf16<<<gG, 256, 0, stream>>>(xb, WT1, h1, N);
  k_agg_bf16<<<gA, 256, 0, stream>>>(h1, dinv, rowptr, csr2, b1, t1, nullptr, N, 1);
  k_gemm_bf16<<<gG, 256, 0, stream>>>(t1, WT2, h2, N);
  k_agg_bf16<<<gA, 256, 0, stream>>>(h2, dinv, rowptr, csr2, b2, nullptr, out, N, 0);
}

// Round 4
// 262.645 us; speedup vs baseline: 1.4936x; 1.0644x over previous
//
#include <hip/hip_runtime.h>

#define NFEAT 128

typedef __attribute__((ext_vector_type(8))) short bf16x8;
typedef __attribute__((ext_vector_type(4))) float f32x4;

__device__ inline ushort f2b(float v) {  // fp32 -> bf16 RNE
  unsigned u = __builtin_bit_cast(unsigned, v);
  return (ushort)((u + 0x7FFFu + ((u >> 16) & 1u)) >> 16);
}

// ---------------- CSR build (XCD-partitioned) ----------------
// Nodes split into 8 contiguous ranges. Block b handles range b&7, edge chunk
// b>>3. blockIdx%8 -> XCD round-robin, so each range's cnt/cursor/csr2 region is
// touched by ONE XCD: atomics are L2-local and csr2 lines merge before eviction
// (R3 showed 8x write-amp: 42MB HBM writes for 4.8MB of csr2 payload).

__global__ __launch_bounds__(256) void k_hist(const int* __restrict__ dst,
                                              int* __restrict__ cnt, int E, int N) {
  int range = blockIdx.x & 7, chunk = blockIdx.x >> 3;
  int lo = (int)(((long long)range * N) >> 3);
  int hi = (int)(((long long)(range + 1) * N) >> 3);
  int base = chunk * 1024;
#pragma unroll
  for (int j = 0; j < 4; j++) {
    int i = base + j * 256 + threadIdx.x;
    if (i < E) {
      int d = dst[i];
      if ((unsigned)(d - lo) < (unsigned)(hi - lo)) atomicAdd(&cnt[d], 1);
    }
  }
}

// scan over PADDED counts (ceil(cnt/4)*4) so agg's unroll-4 loop needs no tail;
// dinv (true count +1 self loop) fused in.
__global__ __launch_bounds__(256) void k_scan_blocks(const int* __restrict__ cnt,
                                                     int* __restrict__ rowptr,
                                                     int* __restrict__ bsum,
                                                     float* __restrict__ dinv, int n) {
  __shared__ int s[256];
  int tid = threadIdx.x;
  int idx = blockIdx.x * 1024 + tid * 4;
  int v[4];
  int sum = 0;
#pragma unroll
  for (int j = 0; j < 4; j++) {
    int c = 0;
    if (idx + j < n) {
      c = cnt[idx + j];
      dinv[idx + j] = rsqrtf((float)(c + 1));
    }
    v[j] = (idx + j < n) ? ((c + 3) & ~3) : 0;
    sum += v[j];
  }
  s[tid] = sum;
  __syncthreads();
  for (int off = 1; off < 256; off <<= 1) {
    int t = (tid >= off) ? s[tid - off] : 0;
    __syncthreads();
    s[tid] += t;
    __syncthreads();
  }
  if (tid == 255) bsum[blockIdx.x] = s[255];
  int run = s[tid] - sum;
#pragma unroll
  for (int j = 0; j < 4; j++) {
    if (idx + j < n) rowptr[idx + j] = run;
    run += v[j];
  }
}

// fused: scan bsum (nb<=256, redundantly per block) + add + cursor init + rowptr[n]
__global__ __launch_bounds__(256) void k_scan_addcur(int* __restrict__ rowptr,
                                                     const int* __restrict__ bsum,
                                                     int* __restrict__ cursor,
                                                     int n, int nb) {
  __shared__ int s[256];
  int tid = threadIdx.x;
  int v = (tid < nb) ? bsum[tid] : 0;
  s[tid] = v;
  __syncthreads();
  for (int off = 1; off < 256; off <<= 1) {
    int t = (tid >= off) ? s[tid - off] : 0;
    __syncthreads();
    s[tid] += t;
    __syncthreads();
  }
  int total = s[255];
  __syncthreads();
  int ex = s[tid] - v;
  __syncthreads();
  s[tid] = ex;
  __syncthreads();
  int i = blockIdx.x * 256 + tid;
  if (i < n) {
    int rp = rowptr[i] + s[i >> 10];
    rowptr[i] = rp;
    cursor[i] = rp;
  }
  if (i == 0) rowptr[n] = total;
}

__global__ __launch_bounds__(256) void k_scatter(const int* __restrict__ src,
                                                 const int* __restrict__ dst,
                                                 const float* __restrict__ dinv,
                                                 int* __restrict__ cursor,
                                                 int2* __restrict__ csr2, int E, int N) {
  int range = blockIdx.x & 7, chunk = blockIdx.x >> 3;
  int lo = (int)(((long long)range * N) >> 3);
  int hi = (int)(((long long)(range + 1) * N) >> 3);
  int base = chunk * 1024;
#pragma unroll
  for (int j = 0; j < 4; j++) {
    int i = base + j * 256 + threadIdx.x;
    if (i < E) {
      int d = dst[i];
      if ((unsigned)(d - lo) < (unsigned)(hi - lo)) {
        int s = src[i];
        int p = atomicAdd(&cursor[d], 1);  // absolute slot (cursor init = rowptr)
        int2 v;
        v.x = s;
        v.y = __float_as_int(dinv[s]);
        csr2[p] = v;
      }
    }
  }
}

// both weights, transpose + cast in one launch; grid 128
__global__ __launch_bounds__(256) void k_cast_w(const float* __restrict__ W1,
                                                const float* __restrict__ W2,
                                                ushort* __restrict__ WT1,
                                                ushort* __restrict__ WT2) {
  int b = blockIdx.x;
  const float* W = (b < 64) ? W1 : W2;
  ushort* WT = (b < 64) ? WT1 : WT2;
  int idx = (b & 63) * 256 + threadIdx.x;
  int k = idx >> 7, nn = idx & 127;
  WT[nn * 128 + k] = f2b(W[idx]);
}

// ---------------- bf16 MFMA GEMM: out[n,128] = A[n,128] @ W[128,128] ----------------
// Block = 128 rows, 4 waves x 32 rows. W^T in LDS (pad 136 -> 2-way bank = free).
// A-frags global->reg, reused across 8 col-tiles. AFP32: A is fp32, convert inline
// (kills the separate 77MB cast pass).

template <bool AFP32>
__global__ __launch_bounds__(256) void k_gemm(const void* __restrict__ Av,
                                              const ushort* __restrict__ WT,
                                              ushort* __restrict__ out, int n) {
  __shared__ ushort sW[128][136];
  int tid = threadIdx.x;
  {
    int r = tid >> 1, hh = tid & 1;
    const uint4* srcp = (const uint4*)(WT + r * 128 + hh * 64);
    uint4* dstp = (uint4*)(&sW[r][hh * 64]);
#pragma unroll
    for (int j = 0; j < 8; j++) dstp[j] = srcp[j];
  }
  __syncthreads();

  int wave = tid >> 6;
  int lane = tid & 63;
  int l16 = lane & 15;
  int quad = lane >> 4;
  int rowBase = blockIdx.x * 128 + wave * 32;

  bf16x8 afrag[2][4];
#pragma unroll
  for (int rt = 0; rt < 2; rt++) {
    int row = rowBase + rt * 16 + l16;
    row = min(row, n - 1);  // OOB rows compute garbage, never stored
    if (AFP32) {
      const float* Ap = (const float*)Av + (size_t)row * NFEAT + quad * 8;
#pragma unroll
      for (int ks = 0; ks < 4; ks++) {
        float4 f0 = *(const float4*)(Ap + ks * 32);
        float4 f1 = *(const float4*)(Ap + ks * 32 + 4);
        ushort t[8] = {f2b(f0.x), f2b(f0.y), f2b(f0.z), f2b(f0.w),
                       f2b(f1.x), f2b(f1.y), f2b(f1.z), f2b(f1.w)};
        afrag[rt][ks] = *(const bf16x8*)t;
      }
    } else {
      const ushort* Ap = (const ushort*)Av + (size_t)row * NFEAT + quad * 8;
#pragma unroll
      for (int ks = 0; ks < 4; ks++) afrag[rt][ks] = *(const bf16x8*)(Ap + ks * 32);
    }
  }

#pragma unroll
  for (int ct = 0; ct < 8; ct++) {
    bf16x8 bfrag[4];
#pragma unroll
    for (int ks = 0; ks < 4; ks++)
      bfrag[ks] = *(const bf16x8*)(&sW[ct * 16 + l16][ks * 32 + quad * 8]);
    f32x4 acc[2] = {{0.f, 0.f, 0.f, 0.f}, {0.f, 0.f, 0.f, 0.f}};
#pragma unroll
    for (int rt = 0; rt < 2; rt++)
#pragma unroll
      for (int ks = 0; ks < 4; ks++)
        acc[rt] = __builtin_amdgcn_mfma_f32_16x16x32_bf16(afrag[rt][ks], bfrag[ks],
                                                          acc[rt], 0, 0, 0);
#pragma unroll
    for (int rt = 0; rt < 2; rt++)
#pragma unroll
      for (int r = 0; r < 4; r++) {
        int row = rowBase + rt * 16 + quad * 4 + r;
        if (row < n) out[(size_t)row * NFEAT + ct * 16 + l16] = f2b(acc[rt][r]);
      }
  }
}

// ---------------- aggregation: 32 lanes/node, 2 nodes/wave ----------------
// Segments padded to x4 with (src=0, w=0) entries -> guard-free unroll-4 loop,
// 8 independent h-gathers in flight per wave at all times.

__global__ __launch_bounds__(256) void k_agg(const ushort* __restrict__ h,
                                             const float* __restrict__ dinv,
                                             const int* __restrict__ rowptr,
                                             const int2* __restrict__ csr2,
                                             const float* __restrict__ bias,
                                             ushort* __restrict__ out_bf,
                                             float* __restrict__ out_f32,
                                             int n, int relu_bf) {
  int node = blockIdx.x * 8 + (threadIdx.x >> 5);
  if (node >= n) return;
  int c = (threadIdx.x & 31) * 4;
  float di = dinv[node];

  uint2 hv = *(const uint2*)(h + (size_t)node * NFEAT + c);
  float a0 = di * __uint_as_float(hv.x << 16);
  float a1 = di * __uint_as_float(hv.x & 0xffff0000u);
  float a2 = di * __uint_as_float(hv.y << 16);
  float a3 = di * __uint_as_float(hv.y & 0xffff0000u);

  int e = rowptr[node], end = rowptr[node + 1];
  for (; e < end; e += 4) {
    int2 p0 = csr2[e], p1 = csr2[e + 1], p2 = csr2[e + 2], p3 = csr2[e + 3];
    uint2 h0 = *(const uint2*)(h + (size_t)p0.x * NFEAT + c);
    uint2 h1 = *(const uint2*)(h + (size_t)p1.x * NFEAT + c);
    uint2 h2 = *(const uint2*)(h + (size_t)p2.x * NFEAT + c);
    uint2 h3 = *(const uint2*)(h + (size_t)p3.x * NFEAT + c);
    float w0 = __int_as_float(p0.y), w1 = __int_as_float(p1.y);
    float w2 = __int_as_float(p2.y), w3 = __int_as_float(p3.y);
    a0 = fmaf(w0, __uint_as_float(h0.x << 16), a0);
    a1 = fmaf(w0, __uint_as_float(h0.x & 0xffff0000u), a1);
    a2 = fmaf(w0, __uint_as_float(h0.y << 16), a2);
    a3 = fmaf(w0, __uint_as_float(h0.y & 0xffff0000u), a3);
    a0 = fmaf(w1, __uint_as_float(h1.x << 16), a0);
    a1 = fmaf(w1, __uint_as_float(h1.x & 0xffff0000u), a1);
    a2 = fmaf(w1, __uint_as_float(h1.y << 16), a2);
    a3 = fmaf(w1, __uint_as_float(h1.y & 0xffff0000u), a3);
    a0 = fmaf(w2, __uint_as_float(h2.x << 16), a0);
    a1 = fmaf(w2, __uint_as_float(h2.x & 0xffff0000u), a1);
    a2 = fmaf(w2, __uint_as_float(h2.y << 16), a2);
    a3 = fmaf(w2, __uint_as_float(h2.y & 0xffff0000u), a3);
    a0 = fmaf(w3, __uint_as_float(h3.x << 16), a0);
    a1 = fmaf(w3, __uint_as_float(h3.x & 0xffff0000u), a1);
    a2 = fmaf(w3, __uint_as_float(h3.y << 16), a2);
    a3 = fmaf(w3, __uint_as_float(h3.y & 0xffff0000u), a3);
  }

  float4 b = *(const float4*)(bias + c);
  float o0 = fmaf(di, a0, b.x);
  float o1 = fmaf(di, a1, b.y);
  float o2 = fmaf(di, a2, b.z);
  float o3 = fmaf(di, a3, b.w);
  if (relu_bf) {
    o0 = fmaxf(o0, 0.f); o1 = fmaxf(o1, 0.f);
    o2 = fmaxf(o2, 0.f); o3 = fmaxf(o3, 0.f);
    uint2 pk;
    pk.x = f2b(o0) | ((unsigned)f2b(o1) << 16);
    pk.y = f2b(o2) | ((unsigned)f2b(o3) << 16);
    *(uint2*)(out_bf + (size_t)node * NFEAT + c) = pk;
  } else {
    float4 o = {o0, o1, o2, o3};
    *(float4*)(out_f32 + (size_t)node * NFEAT + c) = o;
  }
}

// ---------------- launch ----------------

extern "C" void kernel_launch(void* const* d_in, const int* in_sizes, int n_in,
                              void* d_out, int out_size, void* d_ws, size_t ws_size,
                              hipStream_t stream) {
  const float* x = (const float*)d_in[0];
  const float* W1 = (const float*)d_in[1];
  const float* b1 = (const float*)d_in[2];
  const float* W2 = (const float*)d_in[3];
  const float* b2 = (const float*)d_in[4];
  const int* ei = (const int*)d_in[5];

  const int N = in_sizes[0] / NFEAT;
  const int E = in_sizes[5] / 2;
  const int* srcIdx = ei;
  const int* dstIdx = ei + E;

  char* p = (char*)d_ws;
  auto alloc = [&](size_t bytes) {
    char* r = p;
    p += (bytes + 255) & ~(size_t)255;
    return r;
  };
  // cnt and csr2 adjacent -> single memset zeroes counts AND pad entries
  int* cnt = (int*)alloc((size_t)N * 4);
  int2* csr2 = (int2*)alloc((size_t)(E + 3 * N + 8) * 8);  // padded-to-4 segments
  char* memset_end = p;
  int* cursor = (int*)alloc((size_t)N * 4);
  float* dinv = (float*)alloc((size_t)N * 4);
  int* rowptr = (int*)alloc((size_t)(N + 1) * 4);
  int* bsum = (int*)alloc(1024);
  ushort* WT1 = (ushort*)alloc(NFEAT * NFEAT * 2);
  ushort* WT2 = (ushort*)alloc(NFEAT * NFEAT * 2);
  ushort* t1 = (ushort*)alloc((size_t)N * NFEAT * 2);  // agg1 out (bf16)
  ushort* h2 = (ushort*)alloc((size_t)N * NFEAT * 2);  // gemm2 out (bf16)
  ushort* h1 = (ushort*)d_out;  // gemm1 out lives in d_out; dead before agg2 writes
  float* out = (float*)d_out;

  hipMemsetAsync(cnt, 0, (size_t)(memset_end - (char*)cnt), stream);

  int nb = (N + 1023) / 1024;
  int gEx = ((E + 1023) / 1024) * 8;  // XCD-partitioned edge kernels

  k_hist<<<gEx, 256, 0, stream>>>(dstIdx, cnt, E, N);
  k_scan_blocks<<<nb, 256, 0, stream>>>(cnt, rowptr, bsum, dinv, N);
  k_scan_addcur<<<(N + 255) / 256, 256, 0, stream>>>(rowptr, bsum, cursor, N, nb);
  k_scatter<<<gEx, 256, 0, stream>>>(srcIdx, dstIdx, dinv, cursor, csr2, E, N);
  k_cast_w<<<128, 256, 0, stream>>>(W1, W2, WT1, WT2);

  int gG = (N + 127) / 128;
  int gA = (N + 7) / 8;

  k_gemm<true><<<gG, 256, 0, stream>>>(x, WT1, h1, N);
  k_agg<<<gA, 256, 0, stream>>>(h1, dinv, rowptr, csr2, b1, t1, nullptr, N, 1);
  k_gemm<false><<<gG, 256, 0, stream>>>(t1, WT2, h2, N);
  k_agg<<<gA, 256, 0, stream>>>(h2, dinv, rowptr, csr2, b2, nullptr, out, N, 0);
}